// Round 13
// baseline (256.633 us; speedup 1.0000x reference)
//
#include <hip/hip_runtime.h>
#include <math.h>

static constexpr int B_  = 2;
static constexpr int S_  = 2048;
static constexpr int H_  = 16;
static constexpr int DH_ = 64;
static constexpr float SCALE_ = 0.07216878364870322f;   // 1/sqrt(192)

typedef __attribute__((ext_vector_type(8))) short short8;   // 8 x bf16
typedef __attribute__((ext_vector_type(4))) float floatx4;  // MFMA acc

__device__ __forceinline__ float bf2f(unsigned short u) {
    union { unsigned int i; float f; } c; c.i = ((unsigned int)u) << 16; return c.f;
}
__device__ __forceinline__ unsigned short f2bf(float f) {
    union { float f; unsigned int i; } c; c.f = f;
    unsigned int x = c.i;
    unsigned int r = (x + 0x7fffu + ((x >> 16) & 1u)) >> 16;
    if ((x & 0x7f800000u) == 0x7f800000u) r = x >> 16;   // inf/nan passthrough
    return (unsigned short)r;
}
// positive-finite fast path (exp() results): RNE without nan/inf check
__device__ __forceinline__ unsigned short f2bf_pos(float f) {
    union { float f; unsigned int i; } c; c.f = f;
    return (unsigned short)((c.i + 0x7fffu + ((c.i >> 16) & 1u)) >> 16);
}
__device__ __forceinline__ void load_lds16(const unsigned short* g, unsigned short* l) {
    __builtin_amdgcn_global_load_lds(
        (const __attribute__((address_space(1))) unsigned int*)g,
        (__attribute__((address_space(3))) unsigned int*)l, 16, 0, 0);
}

// fp32 -> bf16, row-major copy (x matrix)
__global__ __launch_bounds__(256) void cvt_x(
    const float* __restrict__ in, unsigned short* __restrict__ out)
{
    const int i = blockIdx.x * 256 + threadIdx.x;
    const float4 v = reinterpret_cast<const float4*>(in)[i];
    ushort4 r;
    r.x = f2bf(v.x); r.y = f2bf(v.y); r.z = f2bf(v.z); r.w = f2bf(v.w);
    reinterpret_cast<ushort4*>(out)[i] = r;
}

// in: K=1024 x NN fp32 (row-major)  ->  out: NN x 1024 bf16 (row-major)
template<int NN>
__global__ __launch_bounds__(256) void transcvt(
    const float* __restrict__ in, unsigned short* __restrict__ out)
{
    __shared__ float t[32][33];
    const int n0 = blockIdx.x * 32;
    const int k0 = blockIdx.y * 32;
    const int tn = threadIdx.x & 31, tk = threadIdx.x >> 5;   // tk 0..7
    #pragma unroll
    for (int i = 0; i < 4; ++i)
        t[tk + 8 * i][tn] = in[(size_t)(k0 + tk + 8 * i) * NN + n0 + tn];
    __syncthreads();
    #pragma unroll
    for (int i = 0; i < 4; ++i)
        out[(size_t)(n0 + tk + 8 * i) * 1024 + k0 + tn] = f2bf(t[tn][tk + 8 * i]);
}

// ---------------------------------------------------------------------------
// MFMA GEMM (R9-verified): C(128x128) = A(Mx1024 bf16) * BT(NWx1024 bf16)^T.
// MODE 0 (NW=3072): bias + RoPE epilogue -> Q/K/V bf16 (B,H,S,DH); Q *= SCALE.
// MODE 1 (NW=1024): bias -> fp32 row-major store.
// ---------------------------------------------------------------------------
template<int NW, int MODE>
__global__ __launch_bounds__(256) void gemm_mfma(
    const unsigned short* __restrict__ A, const unsigned short* __restrict__ BT,
    const float* __restrict__ bias,
    unsigned short* __restrict__ O0, unsigned short* __restrict__ O1,
    unsigned short* __restrict__ O2, float* __restrict__ Of)
{
    __shared__ unsigned short As[128 * 32];
    __shared__ unsigned short Bs[128 * 32];

    const int tid  = threadIdx.x;
    const int wave = tid >> 6;
    const int lane = tid & 63;
    const int quad = lane >> 4;
    const int lm   = lane & 15;
    const int wm = (wave >> 1) * 64;
    const int wn = (wave & 1) * 64;
    const int n0 = blockIdx.x * 128;
    const int m0 = blockIdx.y * 128;

    floatx4 acc[4][4] = {};

    const int sr = lane >> 2;
    const int sc = lane & 3;

    for (int k0 = 0; k0 < 1024; k0 += 32) {
        #pragma unroll
        for (int rep = 0; rep < 2; ++rep) {
            const int r = wave * 32 + rep * 16;
            load_lds16(A  + (size_t)(m0 + r + sr) * 1024 + k0 + sc * 8, &As[r * 32]);
            load_lds16(BT + (size_t)(n0 + r + sr) * 1024 + k0 + sc * 8, &Bs[r * 32]);
        }
        __syncthreads();
        short8 af[4], bf[4];
        #pragma unroll
        for (int i = 0; i < 4; ++i) {
            af[i] = *reinterpret_cast<const short8*>(&As[(wm + i * 16 + lm) * 32 + quad * 8]);
            bf[i] = *reinterpret_cast<const short8*>(&Bs[(wn + i * 16 + lm) * 32 + quad * 8]);
        }
        #pragma unroll
        for (int mi = 0; mi < 4; ++mi)
            #pragma unroll
            for (int ni = 0; ni < 4; ++ni)
                acc[mi][ni] = __builtin_amdgcn_mfma_f32_16x16x32_bf16(
                    af[mi], bf[ni], acc[mi][ni], 0, 0, 0);
        __syncthreads();
    }

    if (MODE == 1) {
        #pragma unroll
        for (int ni = 0; ni < 4; ++ni) {
            const int gn = n0 + wn + ni * 16 + lm;
            const float b = bias[gn];
            #pragma unroll
            for (int mi = 0; mi < 4; ++mi) {
                const int gm = m0 + wm + mi * 16 + quad * 4;
                #pragma unroll
                for (int r = 0; r < 4; ++r)
                    Of[(size_t)(gm + r) * 1024 + gn] = acc[mi][ni][r] + b;
            }
        }
    } else {
        const int nbase = n0 + wn;
        const int h   = nbase / 192;
        const int sec = (nbase - h * 192) >> 6;      // 0=q 1=k 2=v
        float bia[4];
        #pragma unroll
        for (int ni = 0; ni < 4; ++ni) bia[ni] = bias[nbase + ni * 16 + lm];
        unsigned short* Out = (sec == 0) ? O0 : ((sec == 1) ? O1 : O2);
        const float qscale = (sec == 0) ? SCALE_ : 1.0f;
        const float nlf = -13.287712379549449f / 32.0f;   // -log2(1e4)/32
        const float invf0 = exp2f((float)lm * nlf);
        const float invf1 = exp2f((float)(lm + 16) * nlf);
        #pragma unroll
        for (int mi = 0; mi < 4; ++mi) {
            #pragma unroll
            for (int r = 0; r < 4; ++r) {
                const int m  = m0 + wm + mi * 16 + quad * 4 + r;
                const int bb = m >> 11;
                const int s  = m & (S_ - 1);
                const size_t obase = ((size_t)(bb * H_ + h) * S_ + s) * DH_;
                if (sec == 2) {
                    #pragma unroll
                    for (int ni = 0; ni < 4; ++ni)
                        Out[obase + ni * 16 + lm] = f2bf(acc[mi][ni][r] + bia[ni]);
                } else {
                    const float a0 = (float)s * invf0, a1 = (float)s * invf1;
                    const float sn0 = __sinf(a0), cs0 = __cosf(a0);
                    const float sn1 = __sinf(a1), cs1 = __cosf(a1);
                    #pragma unroll
                    for (int ni = 0; ni < 4; ++ni) {
                        const int d = ni * 16 + lm;
                        const float v = acc[mi][ni][r]     + bia[ni];
                        const float p = acc[mi][ni ^ 2][r] + bia[ni ^ 2];  // d^32 partner
                        const float cs = (ni & 1) ? cs1 : cs0;
                        const float sn = (ni & 1) ? sn1 : sn0;
                        float res = (d < 32) ? (v * cs - p * sn) : (v * cs + p * sn);
                        Out[obase + d] = f2bf(res * qscale);
                    }
                }
            }
        }
    }
}

// ---------------------------------------------------------------------------
// MFMA flash attention v3: K direct-from-global into B-frags (no K LDS, no
// 16-way conflicts), V^T double-buffered in LDS (one barrier/iter), static-max
// softmax (M=8), software-pipelined next-tile K/V fetch.
// Block = 64 q of one (b,h); wave = 16-q strip. Q pre-scaled by 1/sqrt(F).
// ---------------------------------------------------------------------------
static constexpr int PST = 68;   // Ps row stride (ushorts)
static constexpr int VST = 70;   // VTs row stride (ushorts)

__global__ __launch_bounds__(256) void flash_mfma(
    const unsigned short* __restrict__ Q, const unsigned short* __restrict__ K,
    const unsigned short* __restrict__ V, unsigned short* __restrict__ Ao)
{
    __shared__ unsigned short VTs[2][64 * VST];   // [buf][d][key]
    __shared__ unsigned short Ps[4][16 * PST];    // per-wave P [q][key]

    const int bi = blockIdx.x;
    const int bh = bi & 31;
    const int qt = 31 - (bi >> 5);            // heavy q-tiles first
    const int h  = bh & 15;
    const int b  = bh >> 4;
    const int tid  = threadIdx.x;
    const int wave = tid >> 6;
    const int lane = tid & 63;
    const int quad = lane >> 4;
    const int lm   = lane & 15;

    const unsigned short* Kg = K + (size_t)bh * S_ * DH_;
    const unsigned short* Vg = V + (size_t)bh * S_ * DH_;

    // Q A-frags: rows m=lm of this wave's 16-q strip (fixed across kt)
    const unsigned short* Qrow =
        Q + ((size_t)bh * S_ + (size_t)qt * 64 + wave * 16 + lm) * DH_;
    const short8 aq0 = *reinterpret_cast<const short8*>(Qrow + quad * 8);
    const short8 aq1 = *reinterpret_cast<const short8*>(Qrow + 32 + quad * 8);

    const float slope8 = exp2f(-0.5f * (float)(h + 1)) * 8.0f;  // slope*MAX_BIAS

    float l_run[4] = {};
    floatx4 acc_o[4] = {};
    unsigned short* Pw = &Ps[wave][0];

    // ---- prologue: K B-frags + V rows for kt=0 ----
    short8 bk0[4], bk1[4];            // B-frag halves: key=t*16+lm, d=quad*8(+32)
    #pragma unroll
    for (int t = 0; t < 4; ++t) {
        const unsigned short* kr = Kg + (size_t)(t * 16 + lm) * DH_ + quad * 8;
        bk0[t] = *reinterpret_cast<const short8*>(kr);
        bk1[t] = *reinterpret_cast<const short8*>(kr + 32);
    }
    short8 v0, v1;                    // V[key=lane][d = wave*16 .. +16)
    {
        const unsigned short* vr = Vg + (size_t)lane * DH_ + wave * 16;
        v0 = *reinterpret_cast<const short8*>(vr);
        v1 = *reinterpret_cast<const short8*>(vr + 8);
    }
    {
        unsigned short* vb = &VTs[0][0];
        #pragma unroll
        for (int j = 0; j < 8; ++j) {
            vb[(wave * 16 + j) * VST + lane]     = (unsigned short)v0[j];
            vb[(wave * 16 + 8 + j) * VST + lane] = (unsigned short)v1[j];
        }
    }
    __syncthreads();

    for (int kt = 0; kt <= qt; ++kt) {
        // ---- S = Q K^T (K frags already in registers) ----
        floatx4 sacc[4] = {};
        #pragma unroll
        for (int t = 0; t < 4; ++t) {
            sacc[t] = __builtin_amdgcn_mfma_f32_16x16x32_bf16(aq0, bk0[t], sacc[t], 0, 0, 0);
            sacc[t] = __builtin_amdgcn_mfma_f32_16x16x32_bf16(aq1, bk1[t], sacc[t], 0, 0, 0);
        }

        // ---- prefetch next tile's K frags + V rows (latency hidden below) ----
        if (kt < qt) {
            const unsigned short* Kn = Kg + (size_t)(kt + 1) * 64 * DH_;
            #pragma unroll
            for (int t = 0; t < 4; ++t) {
                const unsigned short* kr = Kn + (size_t)(t * 16 + lm) * DH_ + quad * 8;
                bk0[t] = *reinterpret_cast<const short8*>(kr);
                bk1[t] = *reinterpret_cast<const short8*>(kr + 32);
            }
            const unsigned short* vr =
                Vg + (size_t)((kt + 1) * 64 + lane) * DH_ + wave * 16;
            v0 = *reinterpret_cast<const short8*>(vr);
            v1 = *reinterpret_cast<const short8*>(vr + 8);
        }

        // ---- static-max softmax: p = exp(s + alibi - 8); mask on diag only ----
        const bool diag = (kt == qt);
        #pragma unroll
        for (int r = 0; r < 4; ++r) {
            const int qg = qt * 64 + wave * 16 + quad * 4 + r;
            float ps = 0.0f;
            #pragma unroll
            for (int t = 0; t < 4; ++t) {
                const int kg = kt * 64 + t * 16 + lm;
                float p = __expf(sacc[t][r] + (float)(kg - qg) * slope8 - 8.0f);
                if (diag && kg > qg) p = 0.0f;
                ps += p;
                Pw[(quad * 4 + r) * PST + t * 16 + lm] = f2bf_pos(p);
            }
            l_run[r] += ps;
        }

        // ---- O += P V  (A=P via LDS layout-swap, B=V^T from current buffer) ----
        const unsigned short* vb = &VTs[kt & 1][0];
        const short8 ap0 = *reinterpret_cast<const short8*>(&Pw[lm * PST + quad * 8]);
        const short8 ap1 = *reinterpret_cast<const short8*>(&Pw[lm * PST + 32 + quad * 8]);
        #pragma unroll
        for (int t = 0; t < 4; ++t) {
            const short8 b0 = *reinterpret_cast<const short8*>(&vb[(t * 16 + lm) * VST + quad * 8]);
            const short8 b1 = *reinterpret_cast<const short8*>(&vb[(t * 16 + lm) * VST + 32 + quad * 8]);
            acc_o[t] = __builtin_amdgcn_mfma_f32_16x16x32_bf16(ap0, b0, acc_o[t], 0, 0, 0);
            acc_o[t] = __builtin_amdgcn_mfma_f32_16x16x32_bf16(ap1, b1, acc_o[t], 0, 0, 0);
        }

        // ---- stage next V^T into the other buffer, single barrier ----
        if (kt < qt) {
            unsigned short* vn = &VTs[(kt + 1) & 1][0];
            #pragma unroll
            for (int j = 0; j < 8; ++j) {
                vn[(wave * 16 + j) * VST + lane]     = (unsigned short)v0[j];
                vn[(wave * 16 + 8 + j) * VST + lane] = (unsigned short)v1[j];
            }
        }
        __syncthreads();
    }

    // ---- epilogue: reduce l across lm lanes, O /= l, write ----
    #pragma unroll
    for (int r = 0; r < 4; ++r) {
        float l = l_run[r];
        l += __shfl_xor(l, 1);
        l += __shfl_xor(l, 2);
        l += __shfl_xor(l, 4);
        l += __shfl_xor(l, 8);
        const float inv_l = 1.0f / l;
        const int s = qt * 64 + wave * 16 + quad * 4 + r;
        const size_t obase = ((size_t)(b * S_ + s) * H_ + h) * DH_;
        #pragma unroll
        for (int t = 0; t < 4; ++t)
            Ao[obase + t * 16 + lm] = f2bf(acc_o[t][r] * inv_l);
    }
}

// ---------------------------------------------------------------------------
extern "C" void kernel_launch(void* const* d_in, const int* in_sizes, int n_in,
                              void* d_out, int out_size, void* d_ws, size_t ws_size,
                              hipStream_t stream)
{
    const float *x = nullptr, *w_qkv = nullptr, *b_qkv = nullptr,
                *w_out = nullptr, *b_out = nullptr;
    for (int i = 0; i < n_in; ++i) {
        switch (in_sizes[i]) {
            case 4194304: x     = (const float*)d_in[i]; break;
            case 3145728: w_qkv = (const float*)d_in[i]; break;
            case 3072:    b_qkv = (const float*)d_in[i]; break;
            case 1048576: w_out = (const float*)d_in[i]; break;
            case 1024:    b_out = (const float*)d_in[i]; break;
        }
    }
    if (!x)     x     = (const float*)d_in[0];
    if (!w_qkv) w_qkv = (const float*)d_in[1];
    if (!b_qkv) b_qkv = (const float*)d_in[2];
    if (!w_out) w_out = (const float*)d_in[3];
    if (!b_out) b_out = (const float*)d_in[4];

    float* out = (float*)d_out;                      // fp32 output
    unsigned short* ws16 = (unsigned short*)d_ws;

    // ws (ushort units): xb | wqkvT | woutT | Qb | Kb | Vb | Aob  = 48 MiB
    unsigned short* xb     = ws16;
    unsigned short* wqkvT  = ws16 + (size_t)4194304;
    unsigned short* woutT  = ws16 + (size_t)7340032;
    unsigned short* Qb     = ws16 + (size_t)8388608;
    unsigned short* Kb     = ws16 + (size_t)12582912;
    unsigned short* Vb     = ws16 + (size_t)16777216;
    unsigned short* Aob    = ws16 + (size_t)20971520;

    cvt_x<<<4096, 256, 0, stream>>>(x, xb);
    transcvt<3072><<<dim3(96, 32), 256, 0, stream>>>(w_qkv, wqkvT);
    transcvt<1024><<<dim3(32, 32), 256, 0, stream>>>(w_out, woutT);

    // QKV projection (MFMA) + bias + RoPE (+ Q*SCALE) -> Q/K/V bf16 (B,H,S,DH)
    gemm_mfma<3072, 0><<<dim3(24, 32), 256, 0, stream>>>(
        xb, wqkvT, b_qkv, Qb, Kb, Vb, nullptr);
    // causal flash attention (MFMA v3) + ALiBi -> Aob bf16 (B,S,H*DH)
    flash_mfma<<<dim3(1024), 256, 0, stream>>>(Qb, Kb, Vb, Aob);
    // output projection (MFMA) + bias -> fp32 (B,S,DM)
    gemm_mfma<1024, 1><<<dim3(8, 32), 256, 0, stream>>>(
        Aob, woutT, b_out, nullptr, nullptr, nullptr, out);
}

// Round 14
// 213.815 us; speedup vs baseline: 1.2003x; 1.2003x over previous
//
#include <hip/hip_runtime.h>
#include <math.h>

static constexpr int B_  = 2;
static constexpr int S_  = 2048;
static constexpr int H_  = 16;
static constexpr int DH_ = 64;
static constexpr float SCALE_ = 0.07216878364870322f;   // 1/sqrt(192)

typedef __attribute__((ext_vector_type(8))) short short8;   // 8 x bf16
typedef __attribute__((ext_vector_type(4))) float floatx4;  // MFMA acc

__device__ __forceinline__ float bf2f(unsigned short u) {
    union { unsigned int i; float f; } c; c.i = ((unsigned int)u) << 16; return c.f;
}
__device__ __forceinline__ unsigned short f2bf(float f) {
    union { float f; unsigned int i; } c; c.f = f;
    unsigned int x = c.i;
    unsigned int r = (x + 0x7fffu + ((x >> 16) & 1u)) >> 16;
    if ((x & 0x7f800000u) == 0x7f800000u) r = x >> 16;   // inf/nan passthrough
    return (unsigned short)r;
}
// positive-finite fast path (exp() results): RNE without nan/inf check
__device__ __forceinline__ unsigned short f2bf_pos(float f) {
    union { float f; unsigned int i; } c; c.f = f;
    return (unsigned short)((c.i + 0x7fffu + ((c.i >> 16) & 1u)) >> 16);
}
__device__ __forceinline__ void load_lds16(const unsigned short* g, unsigned short* l) {
    __builtin_amdgcn_global_load_lds(
        (const __attribute__((address_space(1))) unsigned int*)g,
        (__attribute__((address_space(3))) unsigned int*)l, 16, 0, 0);
}

// fp32 -> bf16, row-major copy (x matrix)
__global__ __launch_bounds__(256) void cvt_x(
    const float* __restrict__ in, unsigned short* __restrict__ out)
{
    const int i = blockIdx.x * 256 + threadIdx.x;
    const float4 v = reinterpret_cast<const float4*>(in)[i];
    ushort4 r;
    r.x = f2bf(v.x); r.y = f2bf(v.y); r.z = f2bf(v.z); r.w = f2bf(v.w);
    reinterpret_cast<ushort4*>(out)[i] = r;
}

// in: K=1024 x NN fp32 (row-major)  ->  out: NN x 1024 bf16 (row-major)
template<int NN>
__global__ __launch_bounds__(256) void transcvt(
    const float* __restrict__ in, unsigned short* __restrict__ out)
{
    __shared__ float t[32][33];
    const int n0 = blockIdx.x * 32;
    const int k0 = blockIdx.y * 32;
    const int tn = threadIdx.x & 31, tk = threadIdx.x >> 5;   // tk 0..7
    #pragma unroll
    for (int i = 0; i < 4; ++i)
        t[tk + 8 * i][tn] = in[(size_t)(k0 + tk + 8 * i) * NN + n0 + tn];
    __syncthreads();
    #pragma unroll
    for (int i = 0; i < 4; ++i)
        out[(size_t)(n0 + tk + 8 * i) * 1024 + k0 + tn] = f2bf(t[tn][tk + 8 * i]);
}

// ---------------------------------------------------------------------------
// MFMA GEMM (R9-verified): C(128x128) = A(Mx1024 bf16) * BT(NWx1024 bf16)^T.
// MODE 0 (NW=3072): bias + RoPE epilogue -> Q/K/V bf16 (B,H,S,DH); Q *= SCALE.
// MODE 1 (NW=1024): bias -> fp32 row-major store.
// ---------------------------------------------------------------------------
template<int NW, int MODE>
__global__ __launch_bounds__(256) void gemm_mfma(
    const unsigned short* __restrict__ A, const unsigned short* __restrict__ BT,
    const float* __restrict__ bias,
    unsigned short* __restrict__ O0, unsigned short* __restrict__ O1,
    unsigned short* __restrict__ O2, float* __restrict__ Of)
{
    __shared__ unsigned short As[128 * 32];
    __shared__ unsigned short Bs[128 * 32];

    const int tid  = threadIdx.x;
    const int wave = tid >> 6;
    const int lane = tid & 63;
    const int quad = lane >> 4;
    const int lm   = lane & 15;
    const int wm = (wave >> 1) * 64;
    const int wn = (wave & 1) * 64;
    const int n0 = blockIdx.x * 128;
    const int m0 = blockIdx.y * 128;

    floatx4 acc[4][4] = {};

    const int sr = lane >> 2;
    const int sc = lane & 3;

    for (int k0 = 0; k0 < 1024; k0 += 32) {
        #pragma unroll
        for (int rep = 0; rep < 2; ++rep) {
            const int r = wave * 32 + rep * 16;
            load_lds16(A  + (size_t)(m0 + r + sr) * 1024 + k0 + sc * 8, &As[r * 32]);
            load_lds16(BT + (size_t)(n0 + r + sr) * 1024 + k0 + sc * 8, &Bs[r * 32]);
        }
        __syncthreads();
        short8 af[4], bf[4];
        #pragma unroll
        for (int i = 0; i < 4; ++i) {
            af[i] = *reinterpret_cast<const short8*>(&As[(wm + i * 16 + lm) * 32 + quad * 8]);
            bf[i] = *reinterpret_cast<const short8*>(&Bs[(wn + i * 16 + lm) * 32 + quad * 8]);
        }
        #pragma unroll
        for (int mi = 0; mi < 4; ++mi)
            #pragma unroll
            for (int ni = 0; ni < 4; ++ni)
                acc[mi][ni] = __builtin_amdgcn_mfma_f32_16x16x32_bf16(
                    af[mi], bf[ni], acc[mi][ni], 0, 0, 0);
        __syncthreads();
    }

    if (MODE == 1) {
        #pragma unroll
        for (int ni = 0; ni < 4; ++ni) {
            const int gn = n0 + wn + ni * 16 + lm;
            const float b = bias[gn];
            #pragma unroll
            for (int mi = 0; mi < 4; ++mi) {
                const int gm = m0 + wm + mi * 16 + quad * 4;
                #pragma unroll
                for (int r = 0; r < 4; ++r)
                    Of[(size_t)(gm + r) * 1024 + gn] = acc[mi][ni][r] + b;
            }
        }
    } else {
        const int nbase = n0 + wn;
        const int h   = nbase / 192;
        const int sec = (nbase - h * 192) >> 6;      // 0=q 1=k 2=v
        float bia[4];
        #pragma unroll
        for (int ni = 0; ni < 4; ++ni) bia[ni] = bias[nbase + ni * 16 + lm];
        unsigned short* Out = (sec == 0) ? O0 : ((sec == 1) ? O1 : O2);
        const float qscale = (sec == 0) ? SCALE_ : 1.0f;
        const float nlf = -13.287712379549449f / 32.0f;   // -log2(1e4)/32
        const float invf0 = exp2f((float)lm * nlf);
        const float invf1 = exp2f((float)(lm + 16) * nlf);
        #pragma unroll
        for (int mi = 0; mi < 4; ++mi) {
            #pragma unroll
            for (int r = 0; r < 4; ++r) {
                const int m  = m0 + wm + mi * 16 + quad * 4 + r;
                const int bb = m >> 11;
                const int s  = m & (S_ - 1);
                const size_t obase = ((size_t)(bb * H_ + h) * S_ + s) * DH_;
                if (sec == 2) {
                    #pragma unroll
                    for (int ni = 0; ni < 4; ++ni)
                        Out[obase + ni * 16 + lm] = f2bf(acc[mi][ni][r] + bia[ni]);
                } else {
                    const float a0 = (float)s * invf0, a1 = (float)s * invf1;
                    const float sn0 = __sinf(a0), cs0 = __cosf(a0);
                    const float sn1 = __sinf(a1), cs1 = __cosf(a1);
                    #pragma unroll
                    for (int ni = 0; ni < 4; ++ni) {
                        const int d = ni * 16 + lm;
                        const float v = acc[mi][ni][r]     + bia[ni];
                        const float p = acc[mi][ni ^ 2][r] + bia[ni ^ 2];  // d^32 partner
                        const float cs = (ni & 1) ? cs1 : cs0;
                        const float sn = (ni & 1) ? sn1 : sn0;
                        float res = (d < 32) ? (v * cs - p * sn) : (v * cs + p * sn);
                        Out[obase + d] = f2bf(res * qscale);
                    }
                }
            }
        }
    }
}

// ---------------------------------------------------------------------------
// MFMA flash attention v4: R12 skeleton (K in LDS, 2 barriers, static-max
// softmax) + manual K staging into PADDED stride-68 Ks (16-way conflict ->
// worst 4-way) + next-tile K/V register loads issued right after barrier 1
// (unconditional consumption next iter -> latency hidden under MFMA/softmax).
// ---------------------------------------------------------------------------
static constexpr int KST = 68;   // Ks row stride (ushorts)
static constexpr int PST = 68;   // Ps row stride
static constexpr int VST = 70;   // VTs row stride

__global__ __launch_bounds__(256) void flash_mfma(
    const unsigned short* __restrict__ Q, const unsigned short* __restrict__ K,
    const unsigned short* __restrict__ V, unsigned short* __restrict__ Ao)
{
    __shared__ unsigned short Ks[64 * KST];     // [key][d] padded
    __shared__ unsigned short VTs[64 * VST];    // [d][key]
    __shared__ unsigned short Ps[4][16 * PST];  // per-wave P [q][key]

    const int bi = blockIdx.x;
    const int bh = bi & 31;
    const int qt = 31 - (bi >> 5);            // heavy q-tiles first
    const int h  = bh & 15;
    const int b  = bh >> 4;
    const int tid  = threadIdx.x;
    const int wave = tid >> 6;
    const int lane = tid & 63;
    const int quad = lane >> 4;
    const int lm   = lane & 15;

    const unsigned short* Kg = K + (size_t)bh * S_ * DH_;
    const unsigned short* Vg = V + (size_t)bh * S_ * DH_;

    // Q A-frags: rows m=lm of this wave's 16-q strip (fixed across kt)
    const unsigned short* Qrow =
        Q + ((size_t)bh * S_ + (size_t)qt * 64 + wave * 16 + lm) * DH_;
    const short8 aq0 = *reinterpret_cast<const short8*>(Qrow + quad * 8);
    const short8 aq1 = *reinterpret_cast<const short8*>(Qrow + 32 + quad * 8);

    const float slope8 = exp2f(-0.5f * (float)(h + 1)) * 8.0f;  // slope*MAX_BIAS

    float l_run[4] = {};
    floatx4 acc_o[4] = {};
    unsigned short* Pw = &Ps[wave][0];

    // staging coords: K row = tid>>2 (64 rows), chunk = tid&3 (+4 second half)
    const int srow = tid >> 2;
    const int sc8  = tid & 3;

    // ---- prologue: load kt=0 K/V into registers ----
    short8 ka, kb, va, vb2;
    {
        const unsigned short* kr = Kg + (size_t)srow * DH_ + sc8 * 8;
        ka = *reinterpret_cast<const short8*>(kr);
        kb = *reinterpret_cast<const short8*>(kr + 32);
        const unsigned short* vr = Vg + (size_t)lane * DH_ + wave * 16;
        va  = *reinterpret_cast<const short8*>(vr);
        vb2 = *reinterpret_cast<const short8*>(vr + 8);
    }

    for (int kt = 0; kt <= qt; ++kt) {
        // ---- write staged registers to LDS ----
        *reinterpret_cast<short8*>(&Ks[srow * KST + sc8 * 8])      = ka;
        *reinterpret_cast<short8*>(&Ks[srow * KST + sc8 * 8 + 32]) = kb;
        #pragma unroll
        for (int j = 0; j < 8; ++j) {
            VTs[(wave * 16 + j) * VST + lane]     = (unsigned short)va[j];
            VTs[(wave * 16 + 8 + j) * VST + lane] = (unsigned short)vb2[j];
        }
        __syncthreads();

        // ---- issue next tile's global loads (hidden under MFMA/softmax) ----
        if (kt < qt) {
            const unsigned short* kr =
                Kg + (size_t)((kt + 1) * 64 + srow) * DH_ + sc8 * 8;
            ka = *reinterpret_cast<const short8*>(kr);
            kb = *reinterpret_cast<const short8*>(kr + 32);
            const unsigned short* vr =
                Vg + (size_t)((kt + 1) * 64 + lane) * DH_ + wave * 16;
            va  = *reinterpret_cast<const short8*>(vr);
            vb2 = *reinterpret_cast<const short8*>(vr + 8);
        }

        // ---- S = Q K^T ----
        floatx4 sacc[4] = {};
        #pragma unroll
        for (int t = 0; t < 4; ++t) {
            const short8 b0 = *reinterpret_cast<const short8*>(&Ks[(t * 16 + lm) * KST + quad * 8]);
            const short8 b1 = *reinterpret_cast<const short8*>(&Ks[(t * 16 + lm) * KST + 32 + quad * 8]);
            sacc[t] = __builtin_amdgcn_mfma_f32_16x16x32_bf16(aq0, b0, sacc[t], 0, 0, 0);
            sacc[t] = __builtin_amdgcn_mfma_f32_16x16x32_bf16(aq1, b1, sacc[t], 0, 0, 0);
        }

        // ---- static-max softmax: p = exp(s + alibi - 8); mask on diag only ----
        const bool diag = (kt == qt);
        #pragma unroll
        for (int r = 0; r < 4; ++r) {
            const int qg = qt * 64 + wave * 16 + quad * 4 + r;
            float ps = 0.0f;
            #pragma unroll
            for (int t = 0; t < 4; ++t) {
                const int kg = kt * 64 + t * 16 + lm;
                float p = __expf(sacc[t][r] + (float)(kg - qg) * slope8 - 8.0f);
                if (diag && kg > qg) p = 0.0f;
                ps += p;
                Pw[(quad * 4 + r) * PST + t * 16 + lm] = f2bf_pos(p);
            }
            l_run[r] += ps;
        }

        // ---- O += P V  (A=P via LDS layout-swap, B=V^T) ----
        const short8 ap0 = *reinterpret_cast<const short8*>(&Pw[lm * PST + quad * 8]);
        const short8 ap1 = *reinterpret_cast<const short8*>(&Pw[lm * PST + 32 + quad * 8]);
        #pragma unroll
        for (int t = 0; t < 4; ++t) {
            const short8 b0 = *reinterpret_cast<const short8*>(&VTs[(t * 16 + lm) * VST + quad * 8]);
            const short8 b1 = *reinterpret_cast<const short8*>(&VTs[(t * 16 + lm) * VST + 32 + quad * 8]);
            acc_o[t] = __builtin_amdgcn_mfma_f32_16x16x32_bf16(ap0, b0, acc_o[t], 0, 0, 0);
            acc_o[t] = __builtin_amdgcn_mfma_f32_16x16x32_bf16(ap1, b1, acc_o[t], 0, 0, 0);
        }
        __syncthreads();   // all reads done before next iter's ds_writes
    }

    // ---- epilogue: reduce l across lm lanes, O /= l, write ----
    #pragma unroll
    for (int r = 0; r < 4; ++r) {
        float l = l_run[r];
        l += __shfl_xor(l, 1);
        l += __shfl_xor(l, 2);
        l += __shfl_xor(l, 4);
        l += __shfl_xor(l, 8);
        const float inv_l = 1.0f / l;
        const int s = qt * 64 + wave * 16 + quad * 4 + r;
        const size_t obase = ((size_t)(b * S_ + s) * H_ + h) * DH_;
        #pragma unroll
        for (int t = 0; t < 4; ++t)
            Ao[obase + t * 16 + lm] = f2bf(acc_o[t][r] * inv_l);
    }
}

// ---------------------------------------------------------------------------
extern "C" void kernel_launch(void* const* d_in, const int* in_sizes, int n_in,
                              void* d_out, int out_size, void* d_ws, size_t ws_size,
                              hipStream_t stream)
{
    const float *x = nullptr, *w_qkv = nullptr, *b_qkv = nullptr,
                *w_out = nullptr, *b_out = nullptr;
    for (int i = 0; i < n_in; ++i) {
        switch (in_sizes[i]) {
            case 4194304: x     = (const float*)d_in[i]; break;
            case 3145728: w_qkv = (const float*)d_in[i]; break;
            case 3072:    b_qkv = (const float*)d_in[i]; break;
            case 1048576: w_out = (const float*)d_in[i]; break;
            case 1024:    b_out = (const float*)d_in[i]; break;
        }
    }
    if (!x)     x     = (const float*)d_in[0];
    if (!w_qkv) w_qkv = (const float*)d_in[1];
    if (!b_qkv) b_qkv = (const float*)d_in[2];
    if (!w_out) w_out = (const float*)d_in[3];
    if (!b_out) b_out = (const float*)d_in[4];

    float* out = (float*)d_out;                      // fp32 output
    unsigned short* ws16 = (unsigned short*)d_ws;

    // ws (ushort units): xb | wqkvT | woutT | Qb | Kb | Vb | Aob  = 48 MiB
    unsigned short* xb     = ws16;
    unsigned short* wqkvT  = ws16 + (size_t)4194304;
    unsigned short* woutT  = ws16 + (size_t)7340032;
    unsigned short* Qb     = ws16 + (size_t)8388608;
    unsigned short* Kb     = ws16 + (size_t)12582912;
    unsigned short* Vb     = ws16 + (size_t)16777216;
    unsigned short* Aob    = ws16 + (size_t)20971520;

    cvt_x<<<4096, 256, 0, stream>>>(x, xb);
    transcvt<3072><<<dim3(96, 32), 256, 0, stream>>>(w_qkv, wqkvT);
    transcvt<1024><<<dim3(32, 32), 256, 0, stream>>>(w_out, woutT);

    // QKV projection (MFMA) + bias + RoPE (+ Q*SCALE) -> Q/K/V bf16 (B,H,S,DH)
    gemm_mfma<3072, 0><<<dim3(24, 32), 256, 0, stream>>>(
        xb, wqkvT, b_qkv, Qb, Kb, Vb, nullptr);
    // causal flash attention (MFMA v4) + ALiBi -> Aob bf16 (B,S,H*DH)
    flash_mfma<<<dim3(1024), 256, 0, stream>>>(Qb, Kb, Vb, Aob);
    // output projection (MFMA) + bias -> fp32 (B,S,DM)
    gemm_mfma<1024, 1><<<dim3(8, 32), 256, 0, stream>>>(
        Aob, woutT, b_out, nullptr, nullptr, nullptr, out);
}